// Round 1
// baseline (6660.676 us; speedup 1.0000x reference)
//
#include <hip/hip_runtime.h>
#include <math.h>

#define H 512
#define V 50000
#define B 64
#define S 50
#define STEPS 31
#define G4 2048
static const size_t BV = (size_t)B * V;   // 3,200,000

// workspace offsets (in floats)
#define OFF_XT   0          // xT[512][64]    embedded input, transposed
#define OFF_HT   32768      // hT_state[512][64]  post-attention h (LSTM input)
#define OFF_CT   65536      // cT_state[512][64]  post-attention c
#define OFF_HRT  98304      // hrnT[512][64]  pre-attention LSTM h output
#define OFF_CRT  131072     // cT_rnn[512][64] pre-attention LSTM c output
#define OFF_TOK  163840     // int tok[64]
#define OFF_GP   163904     // gates_part[8][2048][64]
// total ~1.25M floats ~= 5 MB of d_ws

// ---------------- K0: init state (xT from init tokens, h0/c0 transposed) ----
__global__ __launch_bounds__(256) void k0_init(const float* __restrict__ E,
                                               const int* __restrict__ tok0,
                                               const float* __restrict__ h0,
                                               const float* __restrict__ c0,
                                               float* __restrict__ ws) {
    const int b = blockIdx.x;
    const int t = tok0[b];
    for (int k = threadIdx.x; k < H; k += 256) {
        ws[OFF_XT + k * 64 + b] = E[(size_t)t * H + k];
        ws[OFF_HT + k * 64 + b] = h0[b * H + k];
        ws[OFF_CT + k * 64 + b] = c0[b * H + k];
    }
}

// ---------------- K1: gates partial GEMM (split-k=8) ------------------------
// grid 128 = 16 j-tiles x 8 k-splits, block 256 = 128 j x 2 b-groups
__global__ __launch_bounds__(256) void k1_gates(const float* __restrict__ Wih,
                                                const float* __restrict__ Whh,
                                                float* __restrict__ ws) {
    const int tid = threadIdx.x;
    const int jt = blockIdx.x & 15;
    const int ks = blockIdx.x >> 4;
    const int jl = tid & 127;
    const int bg = __builtin_amdgcn_readfirstlane(tid >> 7); // wave-uniform 0/1
    const int j = jt * 128 + jl;
    const int b0 = bg * 32;
    const float* __restrict__ xT = ws + OFF_XT;
    const float* __restrict__ hT = ws + OFF_HT;

    float acc[32];
#pragma unroll
    for (int i = 0; i < 32; i++) acc[i] = 0.f;

    const int k0 = ks * 64;
    const float4* wi4 = (const float4*)(Wih + (size_t)j * H + k0);
    const float4* wh4 = (const float4*)(Whh + (size_t)j * H + k0);
    for (int k4 = 0; k4 < 16; k4++) {
        float4 wi = wi4[k4];
        float4 wh = wh4[k4];
#pragma unroll
        for (int jj = 0; jj < 4; jj++) {
            const float wiv = ((const float*)&wi)[jj];
            const float whv = ((const float*)&wh)[jj];
            const int k = k0 + k4 * 4 + jj;
            const float* xr = xT + k * 64 + b0;
            const float* hr = hT + k * 64 + b0;
#pragma unroll
            for (int bb = 0; bb < 32; bb++)
                acc[bb] += wiv * xr[bb] + whv * hr[bb];
        }
    }
    float* outp = ws + OFF_GP + ((size_t)ks * G4 + j) * 64 + b0;
#pragma unroll
    for (int b4 = 0; b4 < 8; b4++)
        ((float4*)outp)[b4] = make_float4(acc[b4*4], acc[b4*4+1], acc[b4*4+2], acc[b4*4+3]);
}

// ---------------- K2: LSTM finalize -----------------------------------------
// grid 128, block 256: b = tid&63, m = bid*4 + tid>>6
__global__ __launch_bounds__(256) void k2_fin(const float* __restrict__ b_ih,
                                              const float* __restrict__ b_hh,
                                              float* __restrict__ ws) {
    const int tid = threadIdx.x;
    const int b = tid & 63;
    const int m = blockIdx.x * 4 + (tid >> 6);
    const float* __restrict__ gp = ws + OFF_GP;

    float g[4];
#pragma unroll
    for (int gi = 0; gi < 4; gi++) {
        const int j = gi * 512 + m;
        float s = b_ih[j] + b_hh[j];
#pragma unroll
        for (int ks = 0; ks < 8; ks++)
            s += gp[((size_t)ks * G4 + j) * 64 + b];
        g[gi] = s;
    }
    const float ig = 1.f / (1.f + expf(-g[0]));
    const float fg = 1.f / (1.f + expf(-g[1]));
    const float gg = tanhf(g[2]);
    const float og = 1.f / (1.f + expf(-g[3]));
    const float c_prev = ws[OFF_CT + m * 64 + b];
    const float c_rnn = fg * c_prev + ig * gg;
    const float h_rnn = og * tanhf(c_rnn);
    ws[OFF_CRT + m * 64 + b] = c_rnn;
    ws[OFF_HRT + m * 64 + b] = h_rnn;
}

// ---------------- K3: attention for h and c + residual, writes next state ---
// grid 64 (one block per batch elem), block 256 (4 waves)
__global__ __launch_bounds__(256) void k3_attn(const float* __restrict__ enc,
                                               float* __restrict__ ws) {
    const int b = blockIdx.x;
    const int tid = threadIdx.x;
    const int lane = tid & 63;
    const int wv = __builtin_amdgcn_readfirstlane(tid >> 6);

    __shared__ float sc_h[64], sc_c[64], a_h[64], a_c[64];

    float hr[8], cr[8];
#pragma unroll
    for (int i = 0; i < 8; i++) {
        const int k = lane * 8 + i;
        hr[i] = ws[OFF_HRT + k * 64 + b];
        cr[i] = ws[OFF_CRT + k * 64 + b];
    }
    const float scale = 0.044194173824159216f; // 1/sqrt(512)
    for (int s = wv; s < S; s += 4) {
        const float* e = enc + ((size_t)s * B + b) * H + lane * 8;
        float dh = 0.f, dc = 0.f;
#pragma unroll
        for (int i = 0; i < 8; i++) {
            const float ev = e[i];
            dh += ev * hr[i];
            dc += ev * cr[i];
        }
#pragma unroll
        for (int off = 32; off; off >>= 1) {
            dh += __shfl_down(dh, off);
            dc += __shfl_down(dc, off);
        }
        if (lane == 0) { sc_h[s] = dh * scale; sc_c[s] = dc * scale; }
    }
    __syncthreads();
    if (wv < 2) {
        float* sc = wv ? sc_c : sc_h;
        float* a  = wv ? a_c  : a_h;
        float vval = (lane < S) ? sc[lane] : -__builtin_inff();
        float mx = vval;
#pragma unroll
        for (int off = 32; off; off >>= 1) mx = fmaxf(mx, __shfl_xor(mx, off));
        float e = (lane < S) ? expf(vval - mx) : 0.f;
        float sum = e;
#pragma unroll
        for (int off = 32; off; off >>= 1) sum += __shfl_xor(sum, off);
        if (lane < S) a[lane] = e / sum;
    }
    __syncthreads();
    {
        const int kk = tid * 2;   // 256 threads x 2 k each = 512
        float ch0 = 0, ch1 = 0, cc0 = 0, cc1 = 0;
        for (int s = 0; s < S; s++) {
            const float2 e2 = *(const float2*)(enc + ((size_t)s * B + b) * H + kk);
            const float ah = a_h[s], ac = a_c[s];
            ch0 += ah * e2.x; ch1 += ah * e2.y;
            cc0 += ac * e2.x; cc1 += ac * e2.y;
        }
        const float hr0 = ws[OFF_HRT + kk * 64 + b], hr1 = ws[OFF_HRT + (kk + 1) * 64 + b];
        const float cr0 = ws[OFF_CRT + kk * 64 + b], cr1 = ws[OFF_CRT + (kk + 1) * 64 + b];
        ws[OFF_HT + kk * 64 + b] = ch0 + hr0;
        ws[OFF_HT + (kk + 1) * 64 + b] = ch1 + hr1;
        ws[OFF_CT + kk * 64 + b] = cc0 + cr0;
        ws[OFF_CT + (kk + 1) * 64 + b] = cc1 + cr1;
    }
}

// ---------------- K4: logits = h_rnn @ E^T + fc_bias -------------------------
// grid 391, block 256 = 128 vocab rows x 2 b-groups; acc[32] over batch
__global__ __launch_bounds__(256) void k4_logits(const float* __restrict__ E,
                                                 const float* __restrict__ fcb,
                                                 const float* __restrict__ ws,
                                                 float* __restrict__ out,
                                                 int step) {
    const int tid = threadIdx.x;
    const int vt = tid & 127;
    const int bg = __builtin_amdgcn_readfirstlane(tid >> 7); // wave-uniform 0/1
    const int v = blockIdx.x * 128 + vt;
    const bool valid = v < V;
    const int vc = valid ? v : 0;
    const float* __restrict__ hT = ws + OFF_HRT + bg * 32;

    float acc[32];
#pragma unroll
    for (int i = 0; i < 32; i++) acc[i] = 0.f;

    const float4* e4 = (const float4*)(E + (size_t)vc * H);
    for (int k4 = 0; k4 < 128; k4++) {
        const float4 e = e4[k4];
#pragma unroll
        for (int jj = 0; jj < 4; jj++) {
            const float ev = ((const float*)&e)[jj];
            const float* __restrict__ h = hT + (k4 * 4 + jj) * 64;
#pragma unroll
            for (int bb = 0; bb < 32; bb++) acc[bb] += ev * h[bb];
        }
    }
    if (valid) {
        const float bias = fcb[v];
        float* o = out + (size_t)step * BV + (size_t)(bg * 32) * V + v;
#pragma unroll
        for (int bb = 0; bb < 32; bb++) o[(size_t)bb * V] = acc[bb] + bias;
    }
}

// ---------------- K5: argmax (first-max) + token feedback + embed gather ----
// grid 64 (per batch), block 256
__global__ __launch_bounds__(256) void k5_argmax(const float* __restrict__ E,
                                                 float* __restrict__ ws,
                                                 float* __restrict__ out,
                                                 int step) {
    const int b = blockIdx.x;
    const int tid = threadIdx.x;
    const float* __restrict__ lg = out + (size_t)step * BV + (size_t)b * V;

    float best = -__builtin_inff();
    int bi = 0;
    for (int v = tid; v < V; v += 256) {
        const float x = lg[v];
        if (x > best) { best = x; bi = v; }   // strictly greater -> first max
    }
#pragma unroll
    for (int off = 32; off; off >>= 1) {
        const float ov = __shfl_down(best, off);
        const int oi = __shfl_down(bi, off);
        if (ov > best || (ov == best && oi < bi)) { best = ov; bi = oi; }
    }
    __shared__ float wvv[4];
    __shared__ int wii[4];
    __shared__ int stok;
    const int lane = tid & 63, w = tid >> 6;
    if (lane == 0) { wvv[w] = best; wii[w] = bi; }
    __syncthreads();
    if (tid == 0) {
        float bv = wvv[0]; int bj = wii[0];
#pragma unroll
        for (int k = 1; k < 4; k++)
            if (wvv[k] > bv || (wvv[k] == bv && wii[k] < bj)) { bv = wvv[k]; bj = wii[k]; }
        stok = bj;
        ((int*)(ws + OFF_TOK))[b] = bj;
        out[(size_t)STEPS * BV + (size_t)b * STEPS + step] = (float)bj;
    }
    __syncthreads();
    const int t = stok;
    for (int k = tid; k < H; k += 256)
        ws[OFF_XT + k * 64 + b] = E[(size_t)t * H + k];
}

extern "C" void kernel_launch(void* const* d_in, const int* in_sizes, int n_in,
                              void* d_out, int out_size, void* d_ws, size_t ws_size,
                              hipStream_t stream) {
    const float* E    = (const float*)d_in[0];
    const float* fcb  = (const float*)d_in[1];
    const float* Wih  = (const float*)d_in[2];
    const float* Whh  = (const float*)d_in[3];
    const float* bih  = (const float*)d_in[4];
    const float* bhh  = (const float*)d_in[5];
    const float* enc  = (const float*)d_in[6];
    const float* h0   = (const float*)d_in[7];
    const float* c0   = (const float*)d_in[8];
    const int*   tok0 = (const int*)d_in[9];
    float* out = (float*)d_out;
    float* ws  = (float*)d_ws;

    k0_init<<<64, 256, 0, stream>>>(E, tok0, h0, c0, ws);
    for (int t = 0; t < STEPS; t++) {
        k1_gates<<<128, 256, 0, stream>>>(Wih, Whh, ws);
        k2_fin<<<128, 256, 0, stream>>>(bih, bhh, ws);
        k3_attn<<<64, 256, 0, stream>>>(enc, ws);
        k4_logits<<<391, 256, 0, stream>>>(E, fcb, ws, out, t);
        k5_argmax<<<64, 256, 0, stream>>>(E, ws, out, t);
    }
}